// Round 5
// baseline (160.531 us; speedup 1.0000x reference)
//
#include <hip/hip_runtime.h>

typedef unsigned short u16;
typedef unsigned int   u32;
typedef __attribute__((ext_vector_type(8))) short bf16x8;   // 8 bf16 = 4 VGPRs
typedef __attribute__((ext_vector_type(4))) float f32x4;    // MFMA 16x16 accumulator

union F8 { bf16x8 v; u32 u[4]; };

__device__ __forceinline__ u16 f2b(float f) {
    unsigned u = __builtin_bit_cast(unsigned, f);
    return (u16)((u + 0x7FFFu + ((u >> 16) & 1u)) >> 16);   // RNE fp32->bf16
}
__device__ __forceinline__ u32 pkbf(float a, float b) {     // pack 2 bf16
    return ((u32)f2b(b) << 16) | (u32)f2b(a);
}

// ---------------------------------------------------------------------------
// Prep: bf16 MFMA weight fragments. Fragment f at ushort f*512,
// elem(l,i) = W[k = ks*32 + (l>>4)*8 + i][col = nt*16 + (l&15)].
// Used as A-operand of the transposed GEMMs (A-frag of W^T == B-frag of W).
// Bias table expanded to [h][query][key] fp32 at float offset 32768.
// ---------------------------------------------------------------------------
__global__ void prep_kernel(const float* __restrict__ qkv_w,
                            const float* __restrict__ proj_w,
                            const float* __restrict__ bias_tbl,
                            u16* __restrict__ wsb, float* __restrict__ wsf)
{
    int tid = blockIdx.x * 256 + threadIdx.x;
    if (tid < 49152) {                      // qkv_w fragments
        int i = tid & 7, l = (tid >> 3) & 63, f = tid >> 9;
        int nt = f >> 2, ks = f & 3;
        int k = ks * 32 + (l >> 4) * 8 + i;
        int col = nt * 16 + (l & 15);
        wsb[tid] = f2b(qkv_w[k * 384 + col]);
    } else if (tid < 65536) {               // proj_w fragments
        int e = tid - 49152;
        int i = e & 7, l = (e >> 3) & 63, f = e >> 9;
        int nt = f >> 2, ks = f & 3;
        int k = ks * 32 + (l >> 4) * 8 + i;
        int col = nt * 16 + (l & 15);
        wsb[tid] = f2b(proj_w[k * 128 + col]);
    } else if (tid < 66560) {               // bias expand: [h][t1=query][t2=key]
        int e = tid - 65536;
        int h = e >> 8, t1 = (e >> 4) & 15, t2 = e & 15;
        int idx = ((t1 >> 2) - (t2 >> 2) + 3) * 7 + ((t1 & 3) - (t2 & 3) + 3);
        wsf[32768 + e] = bias_tbl[idx * 4 + h];
    }
}

// ---------------------------------------------------------------------------
// Fused window attention: 4 waves/block, TWO windows per wave (A = even wj,
// B = odd wj). Each weight fragment load feeds 2 MFMAs; both windows' V pack
// into one vT tile [128 d][32 tok] (A: cols 0-15, B: 16-31, stride 40 u16),
// so the PV A-fragment is shared and no pad zeroing is needed.
// ---------------------------------------------------------------------------
__global__ __launch_bounds__(256) void winattn_kernel(
    const float* __restrict__ x, const u16* __restrict__ wfrag,
    const float* __restrict__ qkv_b, const float* __restrict__ proj_b,
    const float* __restrict__ biasx, float* __restrict__ out)
{
    __shared__ alignas(16) u16 lds[4][5120];
    const int tid  = threadIdx.x;
    const int wave = tid >> 6, lane = tid & 63;
    const int g = lane >> 4, q16 = lane & 15;
    u16* vT = lds[wave];

    const int wpair = blockIdx.x * 4 + wave;
    const int wid0  = wpair * 2;                 // even window id; B = wid0+1
    const int b = wid0 >> 10, rem = wid0 & 1023, wi = rem >> 5, wj = rem & 31;

    // lane's token rows (token = q16) for windows A and B (wj, wj+1)
    const int nTokA = (wi * 4 + (q16 >> 2)) * 128 + wj * 4 + (q16 & 3);
    const float* xrowA = x + ((long)b * 16384 + nTokA) * 128;
    const float* xrowB = xrowA + 512;            // +4 tokens in the row

    // x^T B-fragments: lane holds x[tok q16][ch = ks*32 + g*8 + i]
    F8 axA[4], axB[4];
    #pragma unroll
    for (int ks = 0; ks < 4; ++ks) {
        const float4* pA = (const float4*)(xrowA + ks * 32 + g * 8);
        float4 a0 = pA[0], a1 = pA[1];
        axA[ks].u[0] = pkbf(a0.x, a0.y); axA[ks].u[1] = pkbf(a0.z, a0.w);
        axA[ks].u[2] = pkbf(a1.x, a1.y); axA[ks].u[3] = pkbf(a1.z, a1.w);
        const float4* pB = (const float4*)(xrowB + ks * 32 + g * 8);
        float4 b0 = pB[0], b1 = pB[1];
        axB[ks].u[0] = pkbf(b0.x, b0.y); axB[ks].u[1] = pkbf(b0.z, b0.w);
        axB[ks].u[2] = pkbf(b1.x, b1.y); axB[ks].u[3] = pkbf(b1.z, b1.w);
    }

    const bf16x8* wv = (const bf16x8*)wfrag;

    // ---- qkv^T GEMM: D[col nt*16+4g+r][tok q16], one frag -> 2 MFMAs ----
    u32 QpkA[8][2], QpkB[8][2], KpkA[8][2], KpkB[8][2];
    #pragma unroll
    for (int nt = 0; nt < 8; ++nt) {        // Q tiles
        float4 bb = *(const float4*)&qkv_b[nt * 16 + 4 * g];
        f32x4 accA = {bb.x, bb.y, bb.z, bb.w}, accB = accA;
        #pragma unroll
        for (int ks = 0; ks < 4; ++ks) {
            bf16x8 frag = wv[(nt * 4 + ks) * 64 + lane];
            accA = __builtin_amdgcn_mfma_f32_16x16x32_bf16(frag, axA[ks].v, accA, 0, 0, 0);
            accB = __builtin_amdgcn_mfma_f32_16x16x32_bf16(frag, axB[ks].v, accB, 0, 0, 0);
        }
        QpkA[nt][0] = pkbf(accA[0], accA[1]); QpkA[nt][1] = pkbf(accA[2], accA[3]);
        QpkB[nt][0] = pkbf(accB[0], accB[1]); QpkB[nt][1] = pkbf(accB[2], accB[3]);
    }
    #pragma unroll
    for (int nt = 8; nt < 16; ++nt) {       // K tiles
        float4 bb = *(const float4*)&qkv_b[nt * 16 + 4 * g];
        f32x4 accA = {bb.x, bb.y, bb.z, bb.w}, accB = accA;
        #pragma unroll
        for (int ks = 0; ks < 4; ++ks) {
            bf16x8 frag = wv[(nt * 4 + ks) * 64 + lane];
            accA = __builtin_amdgcn_mfma_f32_16x16x32_bf16(frag, axA[ks].v, accA, 0, 0, 0);
            accB = __builtin_amdgcn_mfma_f32_16x16x32_bf16(frag, axB[ks].v, accB, 0, 0, 0);
        }
        KpkA[nt - 8][0] = pkbf(accA[0], accA[1]); KpkA[nt - 8][1] = pkbf(accA[2], accA[3]);
        KpkB[nt - 8][0] = pkbf(accB[0], accB[1]); KpkB[nt - 8][1] = pkbf(accB[2], accB[3]);
    }
    #pragma unroll 2
    for (int nt = 16; nt < 24; ++nt) {      // V tiles -> vT LDS [d][32 tok]
        float4 bb = *(const float4*)&qkv_b[nt * 16 + 4 * g];
        f32x4 accA = {bb.x, bb.y, bb.z, bb.w}, accB = accA;
        #pragma unroll
        for (int ks = 0; ks < 4; ++ks) {
            bf16x8 frag = wv[(nt * 4 + ks) * 64 + lane];
            accA = __builtin_amdgcn_mfma_f32_16x16x32_bf16(frag, axA[ks].v, accA, 0, 0, 0);
            accB = __builtin_amdgcn_mfma_f32_16x16x32_bf16(frag, axB[ks].v, accB, 0, 0, 0);
        }
        int dbase = (nt - 16) * 16 + 4 * g;
        #pragma unroll
        for (int r = 0; r < 4; ++r) {
            vT[(dbase + r) * 40 + q16]      = f2b(accA[r]);
            vT[(dbase + r) * 40 + 16 + q16] = f2b(accB[r]);
        }
    }
    __syncthreads();

    // ---- attention ----
    const float scale = 0.17677669529663689f;   // 32^-0.5
    const int s0  = (2 * (g & 1)) * 16 + q16;   // frag-build shfl sources
    const int s1  = s0 + 16;
    const int sel = g >> 1;
    const int tA0 = ((2 * g) * 16 + q16) & 63,       tA1 = (tA0 + 16) & 63;
    const int tB0 = ((2 * g - 4) * 16 + q16) & 63,   tB1 = (tB0 + 16) & 63;

    f32x4 z4 = {0.f, 0.f, 0.f, 0.f};
    u32 OpkA[4][2][2], OpkB[4][2][2];

    #pragma unroll
    for (int h = 0; h < 4; ++h) {
        // qf/kf: [tok/key q16][d g*8+i] from packed D-frags
        F8 qfA, kfA, qfB, kfB;
        #pragma unroll
        for (int j = 0; j < 4; ++j) {
            int src = (j < 2) ? s0 : s1;
            u32 qloA = (u32)__shfl((int)QpkA[2 * h][j & 1], src, 64);
            u32 qhiA = (u32)__shfl((int)QpkA[2 * h + 1][j & 1], src, 64);
            qfA.u[j] = sel ? qhiA : qloA;
            u32 kloA = (u32)__shfl((int)KpkA[2 * h][j & 1], src, 64);
            u32 khiA = (u32)__shfl((int)KpkA[2 * h + 1][j & 1], src, 64);
            kfA.u[j] = sel ? khiA : kloA;
            u32 qloB = (u32)__shfl((int)QpkB[2 * h][j & 1], src, 64);
            u32 qhiB = (u32)__shfl((int)QpkB[2 * h + 1][j & 1], src, 64);
            qfB.u[j] = sel ? qhiB : qloB;
            u32 kloB = (u32)__shfl((int)KpkB[2 * h][j & 1], src, 64);
            u32 khiB = (u32)__shfl((int)KpkB[2 * h + 1][j & 1], src, 64);
            kfB.u[j] = sel ? khiB : kloB;
        }
        // S^T: lane holds S[q=q16][key=4g+r]
        f32x4 sA = __builtin_amdgcn_mfma_f32_16x16x32_bf16(kfA.v, qfA.v, z4, 0, 0, 0);
        f32x4 sB = __builtin_amdgcn_mfma_f32_16x16x32_bf16(kfB.v, qfB.v, z4, 0, 0, 0);
        float4 bias4 = *(const float4*)&biasx[(h * 16 + q16) * 16 + 4 * g];

        float a0 = sA[0] * scale + bias4.x, a1 = sA[1] * scale + bias4.y;
        float a2 = sA[2] * scale + bias4.z, a3 = sA[3] * scale + bias4.w;
        float mA = fmaxf(fmaxf(a0, a1), fmaxf(a2, a3));
        mA = fmaxf(mA, __shfl_xor(mA, 16, 64));
        mA = fmaxf(mA, __shfl_xor(mA, 32, 64));
        float eA0 = __expf(a0 - mA), eA1 = __expf(a1 - mA);
        float eA2 = __expf(a2 - mA), eA3 = __expf(a3 - mA);
        float suA = eA0 + eA1 + eA2 + eA3;
        suA += __shfl_xor(suA, 16, 64);
        suA += __shfl_xor(suA, 32, 64);
        float rsA = 1.0f / suA;
        u32 pkA0 = pkbf(eA0 * rsA, eA1 * rsA), pkA1 = pkbf(eA2 * rsA, eA3 * rsA);

        float b0 = sB[0] * scale + bias4.x, b1 = sB[1] * scale + bias4.y;
        float b2 = sB[2] * scale + bias4.z, b3 = sB[3] * scale + bias4.w;
        float mB = fmaxf(fmaxf(b0, b1), fmaxf(b2, b3));
        mB = fmaxf(mB, __shfl_xor(mB, 16, 64));
        mB = fmaxf(mB, __shfl_xor(mB, 32, 64));
        float eB0 = __expf(b0 - mB), eB1 = __expf(b1 - mB);
        float eB2 = __expf(b2 - mB), eB3 = __expf(b3 - mB);
        float suB = eB0 + eB1 + eB2 + eB3;
        suB += __shfl_xor(suB, 16, 64);
        suB += __shfl_xor(suB, 32, 64);
        float rsB = 1.0f / suB;
        u32 pkB0 = pkbf(eB0 * rsB, eB1 * rsB), pkB1 = pkbf(eB2 * rsB, eB3 * rsB);

        // P B-frags: [key g*8+i][tok q16]. A: keys 0-15 live; B: keys 16-31.
        F8 pfA, pfB;
        pfA.u[0] = (u32)__shfl((int)pkA0, tA0, 64);
        pfA.u[1] = (u32)__shfl((int)pkA1, tA0, 64);
        pfA.u[2] = (u32)__shfl((int)pkA0, tA1, 64);
        pfA.u[3] = (u32)__shfl((int)pkA1, tA1, 64);
        if (g >= 2) { pfA.u[0] = 0; pfA.u[1] = 0; pfA.u[2] = 0; pfA.u[3] = 0; }
        pfB.u[0] = (u32)__shfl((int)pkB0, tB0, 64);
        pfB.u[1] = (u32)__shfl((int)pkB1, tB0, 64);
        pfB.u[2] = (u32)__shfl((int)pkB0, tB1, 64);
        pfB.u[3] = (u32)__shfl((int)pkB1, tB1, 64);
        if (g < 2)  { pfB.u[0] = 0; pfB.u[1] = 0; pfB.u[2] = 0; pfB.u[3] = 0; }

        // O^T = V^T P^T; shared vf A-frag covers both windows' V (keys 0..31)
        #pragma unroll
        for (int dt = 0; dt < 2; ++dt) {
            bf16x8 vf = *(const bf16x8*)&vT[(h * 32 + dt * 16 + q16) * 40 + g * 8];
            f32x4 oA = __builtin_amdgcn_mfma_f32_16x16x32_bf16(vf, pfA.v, z4, 0, 0, 0);
            f32x4 oB = __builtin_amdgcn_mfma_f32_16x16x32_bf16(vf, pfB.v, z4, 0, 0, 0);
            OpkA[h][dt][0] = pkbf(oA[0], oA[1]); OpkA[h][dt][1] = pkbf(oA[2], oA[3]);
            OpkB[h][dt][0] = pkbf(oB[0], oB[1]); OpkB[h][dt][1] = pkbf(oB[2], oB[3]);
        }
    }

    // proj B-frags af: [ch ks*32+g*8+i][tok q16]
    F8 afA[4], afB[4];
    #pragma unroll
    for (int ks = 0; ks < 4; ++ks)
        #pragma unroll
        for (int j = 0; j < 4; ++j) {
            int src = (j < 2) ? s0 : s1;
            u32 loA = (u32)__shfl((int)OpkA[ks][0][j & 1], src, 64);
            u32 hiA = (u32)__shfl((int)OpkA[ks][1][j & 1], src, 64);
            afA[ks].u[j] = sel ? hiA : loA;
            u32 loB = (u32)__shfl((int)OpkB[ks][0][j & 1], src, 64);
            u32 hiB = (u32)__shfl((int)OpkB[ks][1][j & 1], src, 64);
            afB[ks].u[j] = sel ? hiB : loB;
        }

    // ---- proj^T GEMM + store ----
    const long obaseA = ((long)b * 16384 + nTokA) * 128;
    const long obaseB = obaseA + 512;
    #pragma unroll 2
    for (int nt = 0; nt < 8; ++nt) {
        float4 bb = *(const float4*)&proj_b[nt * 16 + 4 * g];
        f32x4 accA = {bb.x, bb.y, bb.z, bb.w}, accB = accA;
        #pragma unroll
        for (int ks = 0; ks < 4; ++ks) {
            bf16x8 frag = wv[(96 + nt * 4 + ks) * 64 + lane];
            accA = __builtin_amdgcn_mfma_f32_16x16x32_bf16(frag, afA[ks].v, accA, 0, 0, 0);
            accB = __builtin_amdgcn_mfma_f32_16x16x32_bf16(frag, afB[ks].v, accB, 0, 0, 0);
        }
        float4 oA; oA.x = accA[0]; oA.y = accA[1]; oA.z = accA[2]; oA.w = accA[3];
        *(float4*)&out[obaseA + nt * 16 + 4 * g] = oA;
        float4 oB; oB.x = accB[0]; oB.y = accB[1]; oB.z = accB[2]; oB.w = accB[3];
        *(float4*)&out[obaseB + nt * 16 + 4 * g] = oB;
    }
}

extern "C" void kernel_launch(void* const* d_in, const int* in_sizes, int n_in,
                              void* d_out, int out_size, void* d_ws, size_t ws_size,
                              hipStream_t stream)
{
    const float* x        = (const float*)d_in[0];
    const float* qkv_w    = (const float*)d_in[3];
    const float* qkv_b    = (const float*)d_in[4];
    const float* proj_w   = (const float*)d_in[5];
    const float* proj_b   = (const float*)d_in[6];
    const float* bias_tbl = (const float*)d_in[7];

    u16*   wsb = (u16*)d_ws;
    float* wsf = (float*)d_ws;

    prep_kernel<<<260, 256, 0, stream>>>(qkv_w, proj_w, bias_tbl, wsb, wsf);
    winattn_kernel<<<2048, 256, 0, stream>>>(x, wsb, qkv_b, proj_b,
                                             wsf + 32768, (float*)d_out);
}

// Round 8
// 142.358 us; speedup vs baseline: 1.1277x; 1.1277x over previous
//
#include <hip/hip_runtime.h>

typedef unsigned short u16;
typedef unsigned int   u32;
typedef __attribute__((ext_vector_type(8))) short bf16x8;   // 8 bf16 = 4 VGPRs
typedef __attribute__((ext_vector_type(4))) short bf16x4;   // 4 bf16 = 2 VGPRs
typedef __attribute__((ext_vector_type(4))) float f32x4;    // MFMA 16x16 accumulator

union F8 { bf16x8 v; u32 u[4]; };
union F4 { bf16x4 v; u32 u[2]; };

__device__ __forceinline__ u16 f2b(float f) {
    unsigned u = __builtin_bit_cast(unsigned, f);
    return (u16)((u + 0x7FFFu + ((u >> 16) & 1u)) >> 16);   // RNE fp32->bf16
}
__device__ __forceinline__ u32 pkbf(float a, float b) {     // RNE pack (proven)
    return ((u32)f2b(b) << 16) | (u32)f2b(a);
}

// K=16 MFMA from packed-pair (bf16x4) operands, built ONLY from the proven
// K=32 instruction: data in k-slots 0-3 (u[0],u[1]), zeros in slots 4-7, on
// BOTH operands -> contraction pairs data with data at matching k, zeros
// elsewhere. Exact. (The _1k legacy builtin NaN'd on gfx950 in R6/R7 — do
// not use unverified MFMA builtins.)
__device__ __forceinline__ f32x4 mfma16(F4 a, F4 b, f32x4 c) {
    F8 a8, b8;
    a8.u[0] = a.u[0]; a8.u[1] = a.u[1]; a8.u[2] = 0; a8.u[3] = 0;
    b8.u[0] = b.u[0]; b8.u[1] = b.u[1]; b8.u[2] = 0; b8.u[3] = 0;
    return __builtin_amdgcn_mfma_f32_16x16x32_bf16(a8.v, b8.v, c, 0, 0, 0);
}

// ---------------------------------------------------------------------------
// Prep: bf16 MFMA weight fragments. Fragment f at ushort f*512,
// elem(l,i) = W[k = ks*32 + (l>>4)*8 + i][col = nt*16 + (l&15)].
// Bias table expanded to [h][query][key] fp32 at float offset 32768.
// ---------------------------------------------------------------------------
__global__ void prep_kernel(const float* __restrict__ qkv_w,
                            const float* __restrict__ proj_w,
                            const float* __restrict__ bias_tbl,
                            u16* __restrict__ wsb, float* __restrict__ wsf)
{
    int tid = blockIdx.x * 256 + threadIdx.x;
    if (tid < 49152) {                      // qkv_w fragments
        int i = tid & 7, l = (tid >> 3) & 63, f = tid >> 9;
        int nt = f >> 2, ks = f & 3;
        int k = ks * 32 + (l >> 4) * 8 + i;
        int col = nt * 16 + (l & 15);
        wsb[tid] = f2b(qkv_w[k * 384 + col]);
    } else if (tid < 65536) {               // proj_w fragments
        int e = tid - 49152;
        int i = e & 7, l = (e >> 3) & 63, f = e >> 9;
        int nt = f >> 2, ks = f & 3;
        int k = ks * 32 + (l >> 4) * 8 + i;
        int col = nt * 16 + (l & 15);
        wsb[tid] = f2b(proj_w[k * 128 + col]);
    } else if (tid < 66560) {               // bias expand: [h][t1=query][t2=key]
        int e = tid - 65536;
        int h = e >> 8, t1 = (e >> 4) & 15, t2 = e & 15;
        int idx = ((t1 >> 2) - (t2 >> 2) + 3) * 7 + ((t1 & 3) - (t2 & 3) + 3);
        wsf[32768 + e] = bias_tbl[idx * 4 + h];
    }
}

// ---------------------------------------------------------------------------
// Fused window attention: 4 waves/block, TWO windows per wave (A=even wj,
// B=odd). qkv/proj weight fragments feed 2 MFMAs each. Attention is shfl-free
// on the QK/PV paths: qkv D-frags [col 4g+r][tok q16] are used DIRECTLY as
// K=16 MFMA operands (r<->i); softmax output is directly the PV B-frag.
// V goes through LDS with ONE __syncthreads ordering write->read.
// ---------------------------------------------------------------------------
__global__ __launch_bounds__(256, 3) void winattn_kernel(
    const float* __restrict__ x, const u16* __restrict__ wfrag,
    const float* __restrict__ qkv_b, const float* __restrict__ proj_b,
    const float* __restrict__ biasx, float* __restrict__ out)
{
    __shared__ alignas(16) u16 lds[4][4608];     // per-wave vT [128 d][36]
    const int tid  = threadIdx.x;
    const int wave = tid >> 6, lane = tid & 63;
    const int g = lane >> 4, q16 = lane & 15;
    u16* vT = lds[wave];

    const int wpair = blockIdx.x * 4 + wave;
    const int wid0  = wpair * 2;                 // window A; B = wid0+1
    const int b = wid0 >> 10, rem = wid0 & 1023, wi = rem >> 5, wj = rem & 31;

    // lane's token rows (token = q16) for windows A and B
    const int nTokA = (wi * 4 + (q16 >> 2)) * 128 + wj * 4 + (q16 & 3);
    const float* xrowA = x + ((long)b * 16384 + nTokA) * 128;
    const float* xrowB = xrowA + 512;

    // x^T B-fragments: lane holds x[tok q16][ch = ks*32 + g*8 + i]
    F8 axA[4], axB[4];
    #pragma unroll
    for (int ks = 0; ks < 4; ++ks) {
        const float4* pA = (const float4*)(xrowA + ks * 32 + g * 8);
        float4 a0 = pA[0], a1 = pA[1];
        axA[ks].u[0] = pkbf(a0.x, a0.y); axA[ks].u[1] = pkbf(a0.z, a0.w);
        axA[ks].u[2] = pkbf(a1.x, a1.y); axA[ks].u[3] = pkbf(a1.z, a1.w);
        const float4* pB = (const float4*)(xrowB + ks * 32 + g * 8);
        float4 b0 = pB[0], b1 = pB[1];
        axB[ks].u[0] = pkbf(b0.x, b0.y); axB[ks].u[1] = pkbf(b0.z, b0.w);
        axB[ks].u[2] = pkbf(b1.x, b1.y); axB[ks].u[3] = pkbf(b1.z, b1.w);
    }

    const bf16x8* wv = (const bf16x8*)wfrag;

    // ---- qkv^T GEMM: D[col nt*16+4g+r][tok q16]; one frag -> 2 MFMAs ----
    u32 QpkA[8][2], QpkB[8][2], KpkA[8][2], KpkB[8][2];
    #pragma unroll
    for (int nt = 0; nt < 8; ++nt) {        // Q tiles
        float4 bb = *(const float4*)&qkv_b[nt * 16 + 4 * g];
        f32x4 accA = {bb.x, bb.y, bb.z, bb.w}, accB = accA;
        #pragma unroll
        for (int ks = 0; ks < 4; ++ks) {
            bf16x8 frag = wv[(nt * 4 + ks) * 64 + lane];
            accA = __builtin_amdgcn_mfma_f32_16x16x32_bf16(frag, axA[ks].v, accA, 0, 0, 0);
            accB = __builtin_amdgcn_mfma_f32_16x16x32_bf16(frag, axB[ks].v, accB, 0, 0, 0);
        }
        QpkA[nt][0] = pkbf(accA[0], accA[1]); QpkA[nt][1] = pkbf(accA[2], accA[3]);
        QpkB[nt][0] = pkbf(accB[0], accB[1]); QpkB[nt][1] = pkbf(accB[2], accB[3]);
    }
    #pragma unroll
    for (int nt = 8; nt < 16; ++nt) {       // K tiles
        float4 bb = *(const float4*)&qkv_b[nt * 16 + 4 * g];
        f32x4 accA = {bb.x, bb.y, bb.z, bb.w}, accB = accA;
        #pragma unroll
        for (int ks = 0; ks < 4; ++ks) {
            bf16x8 frag = wv[(nt * 4 + ks) * 64 + lane];
            accA = __builtin_amdgcn_mfma_f32_16x16x32_bf16(frag, axA[ks].v, accA, 0, 0, 0);
            accB = __builtin_amdgcn_mfma_f32_16x16x32_bf16(frag, axB[ks].v, accB, 0, 0, 0);
        }
        KpkA[nt - 8][0] = pkbf(accA[0], accA[1]); KpkA[nt - 8][1] = pkbf(accA[2], accA[3]);
        KpkB[nt - 8][0] = pkbf(accB[0], accB[1]); KpkB[nt - 8][1] = pkbf(accB[2], accB[3]);
    }
    #pragma unroll 2
    for (int nt = 16; nt < 24; ++nt) {      // V tiles -> vT [d][A:0-15|B:16-31]
        float4 bb = *(const float4*)&qkv_b[nt * 16 + 4 * g];
        f32x4 accA = {bb.x, bb.y, bb.z, bb.w}, accB = accA;
        #pragma unroll
        for (int ks = 0; ks < 4; ++ks) {
            bf16x8 frag = wv[(nt * 4 + ks) * 64 + lane];
            accA = __builtin_amdgcn_mfma_f32_16x16x32_bf16(frag, axA[ks].v, accA, 0, 0, 0);
            accB = __builtin_amdgcn_mfma_f32_16x16x32_bf16(frag, axB[ks].v, accB, 0, 0, 0);
        }
        int dbase = (nt - 16) * 16 + 4 * g;
        #pragma unroll
        for (int r = 0; r < 4; ++r) {
            vT[(dbase + r) * 36 + q16]      = f2b(accA[r]);
            vT[(dbase + r) * 36 + 16 + q16] = f2b(accB[r]);
        }
    }
    __syncthreads();    // orders cross-lane vT writes before reads

    // ---- attention: K=16 MFMAs, zero shfl on QK/PV paths ----
    const float scale = 0.17677669529663689f;   // 32^-0.5
    f32x4 z4 = {0.f, 0.f, 0.f, 0.f};
    u32 OpkA[8][2], OpkB[8][2];                 // O^T D-frags per 16-d chunk

    #pragma unroll
    for (int h = 0; h < 4; ++h) {
        // S^T = K Q^T : D-frags of K/Q used directly as A/B (chunks 2h, 2h+1)
        F4 ka0, ka1, qa0, qa1, kb0, kb1, qb0, qb1;
        ka0.u[0] = KpkA[2*h][0];   ka0.u[1] = KpkA[2*h][1];
        ka1.u[0] = KpkA[2*h+1][0]; ka1.u[1] = KpkA[2*h+1][1];
        qa0.u[0] = QpkA[2*h][0];   qa0.u[1] = QpkA[2*h][1];
        qa1.u[0] = QpkA[2*h+1][0]; qa1.u[1] = QpkA[2*h+1][1];
        kb0.u[0] = KpkB[2*h][0];   kb0.u[1] = KpkB[2*h][1];
        kb1.u[0] = KpkB[2*h+1][0]; kb1.u[1] = KpkB[2*h+1][1];
        qb0.u[0] = QpkB[2*h][0];   qb0.u[1] = QpkB[2*h][1];
        qb1.u[0] = QpkB[2*h+1][0]; qb1.u[1] = QpkB[2*h+1][1];
        f32x4 sA = mfma16(ka0, qa0, z4); sA = mfma16(ka1, qa1, sA);
        f32x4 sB = mfma16(kb0, qb0, z4); sB = mfma16(kb1, qb1, sB);

        // lane holds S^T[key 4g+r][q q16]; softmax over keys (r + xor16/32)
        float4 bias4 = *(const float4*)&biasx[(h * 16 + q16) * 16 + 4 * g];

        float a0 = sA[0] * scale + bias4.x, a1 = sA[1] * scale + bias4.y;
        float a2 = sA[2] * scale + bias4.z, a3 = sA[3] * scale + bias4.w;
        float mA = fmaxf(fmaxf(a0, a1), fmaxf(a2, a3));
        mA = fmaxf(mA, __shfl_xor(mA, 16, 64));
        mA = fmaxf(mA, __shfl_xor(mA, 32, 64));
        float eA0 = __expf(a0 - mA), eA1 = __expf(a1 - mA);
        float eA2 = __expf(a2 - mA), eA3 = __expf(a3 - mA);
        float suA = eA0 + eA1 + eA2 + eA3;
        suA += __shfl_xor(suA, 16, 64);
        suA += __shfl_xor(suA, 32, 64);
        float rsA = 1.0f / suA;
        F4 pA; pA.u[0] = pkbf(eA0 * rsA, eA1 * rsA); pA.u[1] = pkbf(eA2 * rsA, eA3 * rsA);

        float b0 = sB[0] * scale + bias4.x, b1 = sB[1] * scale + bias4.y;
        float b2 = sB[2] * scale + bias4.z, b3 = sB[3] * scale + bias4.w;
        float mB = fmaxf(fmaxf(b0, b1), fmaxf(b2, b3));
        mB = fmaxf(mB, __shfl_xor(mB, 16, 64));
        mB = fmaxf(mB, __shfl_xor(mB, 32, 64));
        float eB0 = __expf(b0 - mB), eB1 = __expf(b1 - mB);
        float eB2 = __expf(b2 - mB), eB3 = __expf(b3 - mB);
        float suB = eB0 + eB1 + eB2 + eB3;
        suB += __shfl_xor(suB, 16, 64);
        suB += __shfl_xor(suB, 32, 64);
        float rsB = 1.0f / suB;
        F4 pB; pB.u[0] = pkbf(eB0 * rsB, eB1 * rsB); pB.u[1] = pkbf(eB2 * rsB, eB3 * rsB);

        // O^T = V^T P^T : psm is directly the B-frag; V^T A-frag is a b64 read
        #pragma unroll
        for (int dt = 0; dt < 2; ++dt) {
            int row = (h * 32 + dt * 16 + q16) * 36 + 4 * g;
            F4 vfA = *(const F4*)&vT[row];
            F4 vfB = *(const F4*)&vT[row + 16];
            f32x4 oA = mfma16(vfA, pA, z4);
            f32x4 oB = mfma16(vfB, pB, z4);
            OpkA[2*h+dt][0] = pkbf(oA[0], oA[1]); OpkA[2*h+dt][1] = pkbf(oA[2], oA[3]);
            OpkB[2*h+dt][0] = pkbf(oB[0], oB[1]); OpkB[2*h+dt][1] = pkbf(oB[2], oB[3]);
        }
    }

    // proj B-frags af: [ch ks*32+g*8+i][tok q16] via packed-pair shfl
    const int s0  = (2 * (g & 1)) * 16 + q16;
    const int s1  = s0 + 16;
    const int sel = g >> 1;
    F8 afA[4], afB[4];
    #pragma unroll
    for (int ks = 0; ks < 4; ++ks)
        #pragma unroll
        for (int j = 0; j < 4; ++j) {
            int src = (j < 2) ? s0 : s1;
            u32 loA = (u32)__shfl((int)OpkA[2*ks][j & 1], src, 64);
            u32 hiA = (u32)__shfl((int)OpkA[2*ks+1][j & 1], src, 64);
            afA[ks].u[j] = sel ? hiA : loA;
            u32 loB = (u32)__shfl((int)OpkB[2*ks][j & 1], src, 64);
            u32 hiB = (u32)__shfl((int)OpkB[2*ks+1][j & 1], src, 64);
            afB[ks].u[j] = sel ? hiB : loB;
        }

    // ---- proj^T GEMM + store ----
    const long obaseA = ((long)b * 16384 + nTokA) * 128;
    const long obaseB = obaseA + 512;
    #pragma unroll 2
    for (int nt = 0; nt < 8; ++nt) {
        float4 bb = *(const float4*)&proj_b[nt * 16 + 4 * g];
        f32x4 accA = {bb.x, bb.y, bb.z, bb.w}, accB = accA;
        #pragma unroll
        for (int ks = 0; ks < 4; ++ks) {
            bf16x8 frag = wv[(96 + nt * 4 + ks) * 64 + lane];
            accA = __builtin_amdgcn_mfma_f32_16x16x32_bf16(frag, afA[ks].v, accA, 0, 0, 0);
            accB = __builtin_amdgcn_mfma_f32_16x16x32_bf16(frag, afB[ks].v, accB, 0, 0, 0);
        }
        float4 oA; oA.x = accA[0]; oA.y = accA[1]; oA.z = accA[2]; oA.w = accA[3];
        *(float4*)&out[obaseA + nt * 16 + 4 * g] = oA;
        float4 oB; oB.x = accB[0]; oB.y = accB[1]; oB.z = accB[2]; oB.w = accB[3];
        *(float4*)&out[obaseB + nt * 16 + 4 * g] = oB;
    }
}

extern "C" void kernel_launch(void* const* d_in, const int* in_sizes, int n_in,
                              void* d_out, int out_size, void* d_ws, size_t ws_size,
                              hipStream_t stream)
{
    const float* x        = (const float*)d_in[0];
    const float* qkv_w    = (const float*)d_in[3];
    const float* qkv_b    = (const float*)d_in[4];
    const float* proj_w   = (const float*)d_in[5];
    const float* proj_b   = (const float*)d_in[6];
    const float* bias_tbl = (const float*)d_in[7];

    u16*   wsb = (u16*)d_ws;
    float* wsf = (float*)d_ws;

    prep_kernel<<<260, 256, 0, stream>>>(qkv_w, proj_w, bias_tbl, wsb, wsf);
    winattn_kernel<<<2048, 256, 0, stream>>>(x, wsb, qkv_b, proj_b,
                                             wsf + 32768, (float*)d_out);
}